// Round 1
// baseline (9035.461 us; speedup 1.0000x reference)
//
#include <hip/hip_runtime.h>

#define NN 50000
#define NE 600000
#define NR 16
#define NG 128
#define TS 128
#define NTILES 4704   // >= sum_r ceil(cnt_r/128) <= E/128 + 16

// ---------------- sort-by-relation (counting sort, nondeterministic in-bucket order) ----------------

__global__ void k_zero(int* bcnt, int* cursor, float* hg, float* gcnt) {
    int i = blockIdx.x * 256 + threadIdx.x;
    if (i < NR) { bcnt[i] = 0; cursor[i] = 0; }
    if (i < NG) gcnt[i] = 0.f;
    if (i < NG * 128) hg[i] = 0.f;
}

__global__ void k_hist(const int* __restrict__ rel, int* __restrict__ bcnt) {
    __shared__ int lh[NR];
    if (threadIdx.x < NR) lh[threadIdx.x] = 0;
    __syncthreads();
    for (int e = blockIdx.x * blockDim.x + threadIdx.x; e < NE; e += gridDim.x * blockDim.x)
        atomicAdd(&lh[rel[e]], 1);
    __syncthreads();
    if (threadIdx.x < NR) atomicAdd(&bcnt[threadIdx.x], lh[threadIdx.x]);
}

__global__ void k_scan(const int* __restrict__ bcnt, int* __restrict__ boff, int* __restrict__ tstart) {
    if (threadIdx.x == 0 && blockIdx.x == 0) {
        int o = 0, t = 0;
        for (int r = 0; r < NR; ++r) {
            boff[r] = o; tstart[r] = t;
            o += bcnt[r];
            t += (bcnt[r] + TS - 1) / TS;
        }
        boff[NR] = o; tstart[NR] = t;
    }
}

__global__ void k_scatter(const int* __restrict__ rel, const int* __restrict__ boff,
                          int* __restrict__ cursor, int* __restrict__ sorted) {
    __shared__ int lh[NR];
    const int CH = 4096;
    int e0 = blockIdx.x * CH;
    if (threadIdx.x < NR) lh[threadIdx.x] = 0;
    __syncthreads();
    for (int i = threadIdx.x; i < CH; i += 256) {
        int e = e0 + i;
        if (e < NE) atomicAdd(&lh[rel[e]], 1);
    }
    __syncthreads();
    if (threadIdx.x < NR) {
        int c = lh[threadIdx.x];
        lh[threadIdx.x] = (c > 0) ? atomicAdd(&cursor[threadIdx.x], c) : 0;
    }
    __syncthreads();
    for (int i = threadIdx.x; i < CH; i += 256) {
        int e = e0 + i;
        if (e < NE) {
            int r = rel[e];
            int p = atomicAdd(&lh[r], 1);
            sorted[boff[r] + p] = e;
        }
    }
}

// ---------------- self-loop GEMM: agg = h @ W_loop + b (plain store) ----------------

template<int DIN, int DOUT>
__global__ __launch_bounds__(256)
void k_selfloop(const float* __restrict__ h, const float* __restrict__ W,
                const float* __restrict__ bias, float* __restrict__ agg) {
    __shared__ float As[8][TS];
    __shared__ float Bs[8][TS];
    const int tid = threadIdx.x;
    const int row0 = blockIdx.x * TS;
    const int col0 = blockIdx.y * TS;
    const int tm = tid >> 4, tn = tid & 15;
    const int lm = tid >> 1, lk = (tid & 1) * 4;
    const int lbk = tid >> 5, lbn = (tid & 31) * 4;
    float acc[8][8];
#pragma unroll
    for (int i = 0; i < 8; ++i)
#pragma unroll
        for (int j = 0; j < 8; ++j) acc[i][j] = 0.f;
    int arow = row0 + lm; if (arow >= NN) arow = NN - 1;
    for (int k0 = 0; k0 < DIN; k0 += 8) {
        float4 av = *reinterpret_cast<const float4*>(h + (size_t)arow * DIN + k0 + lk);
        float4 bv = *reinterpret_cast<const float4*>(W + (size_t)(k0 + lbk) * DOUT + col0 + lbn);
        __syncthreads();
        As[lk + 0][lm] = av.x;
        As[lk + 1][lm] = av.y;
        As[lk + 2][lm] = av.z;
        As[lk + 3][lm] = av.w;
        *reinterpret_cast<float4*>(&Bs[lbk][lbn]) = bv;
        __syncthreads();
#pragma unroll
        for (int k = 0; k < 8; ++k) {
            float a[8], b[8];
            *reinterpret_cast<float4*>(&a[0]) = *reinterpret_cast<const float4*>(&As[k][tm * 8]);
            *reinterpret_cast<float4*>(&a[4]) = *reinterpret_cast<const float4*>(&As[k][tm * 8 + 4]);
            *reinterpret_cast<float4*>(&b[0]) = *reinterpret_cast<const float4*>(&Bs[k][tn * 8]);
            *reinterpret_cast<float4*>(&b[4]) = *reinterpret_cast<const float4*>(&Bs[k][tn * 8 + 4]);
#pragma unroll
            for (int i = 0; i < 8; ++i)
#pragma unroll
                for (int j = 0; j < 8; ++j) acc[i][j] += a[i] * b[j];
        }
    }
#pragma unroll
    for (int i = 0; i < 8; ++i) {
        int r = row0 + tm * 8 + i;
        if (r < NN) {
#pragma unroll
            for (int j = 0; j < 8; ++j) {
                int c = col0 + tn * 8 + j;
                agg[(size_t)r * DOUT + c] = acc[i][j] + bias[c];
            }
        }
    }
}

// ---------------- edge GEMM: for rel bucket tiles, agg[dst] += h[src] @ W_rel[r] (atomic) ----------------

template<int DIN, int DOUT>
__global__ __launch_bounds__(256)
void k_edge(const float* __restrict__ h, const float* __restrict__ Wrel,
            const int* __restrict__ src, const int* __restrict__ dst,
            const int* __restrict__ sorted, const int* __restrict__ boff,
            const int* __restrict__ tstart, float* __restrict__ agg) {
    const int b = blockIdx.x;
    if (b >= tstart[NR]) return;
    int r = 0;
    for (int q = 1; q < NR; ++q) r += (b >= tstart[q]) ? 1 : 0;
    const int e0 = boff[r] + (b - tstart[r]) * TS;
    int cnt = boff[r + 1] - e0;
    if (cnt > TS) cnt = TS;

    __shared__ float As[8][TS];
    __shared__ float Bs[8][TS];
    __shared__ int s_src[TS], s_dst[TS];
    const int tid = threadIdx.x;
    if (tid < TS) {
        int ei = e0 + tid; if (ei >= NE) ei = NE - 1;
        int e = sorted[ei];
        s_src[tid] = src[e];
        s_dst[tid] = dst[e];
    }
    __syncthreads();

    const float* W = Wrel + (size_t)r * DIN * DOUT;
    const int col0 = blockIdx.y * TS;
    const int tm = tid >> 4, tn = tid & 15;
    const int lm = tid >> 1, lk = (tid & 1) * 4;
    const int lbk = tid >> 5, lbn = (tid & 31) * 4;
    const int arow = s_src[lm];
    float acc[8][8];
#pragma unroll
    for (int i = 0; i < 8; ++i)
#pragma unroll
        for (int j = 0; j < 8; ++j) acc[i][j] = 0.f;

    for (int k0 = 0; k0 < DIN; k0 += 8) {
        float4 av = *reinterpret_cast<const float4*>(h + (size_t)arow * DIN + k0 + lk);
        float4 bv = *reinterpret_cast<const float4*>(W + (size_t)(k0 + lbk) * DOUT + col0 + lbn);
        __syncthreads();
        As[lk + 0][lm] = av.x;
        As[lk + 1][lm] = av.y;
        As[lk + 2][lm] = av.z;
        As[lk + 3][lm] = av.w;
        *reinterpret_cast<float4*>(&Bs[lbk][lbn]) = bv;
        __syncthreads();
#pragma unroll
        for (int k = 0; k < 8; ++k) {
            float a[8], bb[8];
            *reinterpret_cast<float4*>(&a[0]) = *reinterpret_cast<const float4*>(&As[k][tm * 8]);
            *reinterpret_cast<float4*>(&a[4]) = *reinterpret_cast<const float4*>(&As[k][tm * 8 + 4]);
            *reinterpret_cast<float4*>(&bb[0]) = *reinterpret_cast<const float4*>(&Bs[k][tn * 8]);
            *reinterpret_cast<float4*>(&bb[4]) = *reinterpret_cast<const float4*>(&Bs[k][tn * 8 + 4]);
#pragma unroll
            for (int i = 0; i < 8; ++i)
#pragma unroll
                for (int j = 0; j < 8; ++j) acc[i][j] += a[i] * bb[j];
        }
    }
#pragma unroll
    for (int i = 0; i < 8; ++i) {
        int m = tm * 8 + i;
        if (m < cnt) {
            int dn = s_dst[m];
#pragma unroll
            for (int j = 0; j < 8; ++j) {
                atomicAdd(&agg[(size_t)dn * DOUT + col0 + tn * 8 + j], acc[i][j]);
            }
        }
    }
}

// ---------------- elementwise / pooling / MLP ----------------

__global__ void k_relu(const float* __restrict__ in, float* __restrict__ out, int n) {
    for (int i = blockIdx.x * blockDim.x + threadIdx.x; i < n; i += gridDim.x * blockDim.x) {
        float v = in[i];
        out[i] = v > 0.f ? v : 0.f;
    }
}

__global__ void k_pool(const float* __restrict__ h, const int* __restrict__ gid,
                       float* __restrict__ hg, float* __restrict__ gcnt) {
    const int c = threadIdx.x;  // 128 cols
    int n0 = blockIdx.x * 128;
    if (n0 >= NN) return;
    int cur = gid[n0];
    float run = 0.f, crun = 0.f;
    for (int i = 0; i < 128; ++i) {
        int n = n0 + i;
        if (n >= NN) break;
        int g = gid[n];
        if (g != cur) {
            atomicAdd(&hg[cur * 128 + c], run);
            if (c == 0) atomicAdd(&gcnt[cur], crun);
            run = 0.f; crun = 0.f; cur = g;
        }
        run += h[(size_t)n * 128 + c];
        crun += 1.f;
    }
    atomicAdd(&hg[cur * 128 + c], run);
    if (c == 0) atomicAdd(&gcnt[cur], crun);
}

__global__ void k_div(float* hg, const float* __restrict__ gcnt) {
    int i = blockIdx.x * 256 + threadIdx.x;
    if (i < NG * 128) {
        int g = i >> 7;
        float c = gcnt[g];
        hg[i] /= (c > 1.f ? c : 1.f);
    }
}

template<int DIN, int DOUT, bool RELU>
__global__ void k_mlp(const float* __restrict__ in, const float* __restrict__ W,
                      const float* __restrict__ bias, float* __restrict__ out) {
    int g = blockIdx.x;
    int c = blockIdx.y * 256 + threadIdx.x;
    if (c >= DOUT) return;
    float acc = bias[c];
    for (int k = 0; k < DIN; ++k) acc += in[g * DIN + k] * W[k * DOUT + c];
    if (RELU) acc = acc > 0.f ? acc : 0.f;
    out[g * DOUT + c] = acc;
}

__global__ void k_cls(const float* __restrict__ in, const float* __restrict__ Wc,
                      const float* __restrict__ bc, float* __restrict__ out) {
    int g = blockIdx.x * blockDim.x + threadIdx.x;
    if (g >= NG) return;
    float logit[8];
#pragma unroll
    for (int c = 0; c < 8; ++c) logit[c] = bc[c];
    for (int k = 0; k < 128; ++k) {
        float v = in[g * 128 + k];
#pragma unroll
        for (int c = 0; c < 8; ++c) logit[c] += v * Wc[k * 8 + c];
    }
    float m = logit[0];
#pragma unroll
    for (int c = 1; c < 8; ++c) m = logit[c] > m ? logit[c] : m;
    float s = 0.f;
    float e[8];
#pragma unroll
    for (int c = 0; c < 8; ++c) { e[c] = expf(logit[c] - m); s += e[c]; }
    float inv = 1.f / s;
#pragma unroll
    for (int c = 0; c < 8; ++c) out[g * 8 + c] = e[c] * inv;
}

// ---------------- launcher ----------------

extern "C" void kernel_launch(void* const* d_in, const int* in_sizes, int n_in,
                              void* d_out, int out_size, void* d_ws, size_t ws_size,
                              hipStream_t stream) {
    const float* h0   = (const float*)d_in[0];
    const int* src    = (const int*)d_in[1];
    const int* dst    = (const int*)d_in[2];
    const int* rel    = (const int*)d_in[3];
    const int* gid    = (const int*)d_in[4];
    const float* Wr0  = (const float*)d_in[5];
    const float* Wl0  = (const float*)d_in[6];
    const float* b0   = (const float*)d_in[7];
    const float* Wr1  = (const float*)d_in[8];
    const float* Wl1  = (const float*)d_in[9];
    const float* b1   = (const float*)d_in[10];
    const float* Wr2  = (const float*)d_in[11];
    const float* Wl2  = (const float*)d_in[12];
    const float* b2   = (const float*)d_in[13];
    const float* Wh0  = (const float*)d_in[14];
    const float* bh0  = (const float*)d_in[15];
    const float* Wh1  = (const float*)d_in[16];
    const float* bh1  = (const float*)d_in[17];
    const float* Wh2  = (const float*)d_in[18];
    const float* bh2  = (const float*)d_in[19];
    const float* Wc   = (const float*)d_in[20];
    const float* bc   = (const float*)d_in[21];
    float* out = (float*)d_out;

    // workspace layout (~105 MB)
    float* bufA  = (float*)d_ws;                       // [NN,256]
    float* bufB  = bufA + (size_t)NN * 256;            // [NN,256]
    int* sorted  = (int*)(bufB + (size_t)NN * 256);    // [NE]
    int* bcnt    = sorted + NE;                        // [NR]
    int* boff    = bcnt + NR;                          // [NR+1]
    int* tstart  = boff + NR + 1;                      // [NR+1]
    int* cursor  = tstart + NR + 1;                    // [NR]
    float* hg    = (float*)(cursor + NR);              // [NG,128]
    float* gcnt  = hg + NG * 128;                      // [NG]
    float* mlpA  = gcnt + NG;                          // [NG,256]
    float* mlpB  = mlpA + NG * 256;                    // [NG,256]

    // sort edges by relation
    k_zero<<<64, 256, 0, stream>>>(bcnt, cursor, hg, gcnt);
    k_hist<<<256, 256, 0, stream>>>(rel, bcnt);
    k_scan<<<1, 64, 0, stream>>>(bcnt, boff, tstart);
    k_scatter<<<(NE + 4095) / 4096, 256, 0, stream>>>(rel, boff, cursor, sorted);

    const int RB = (NN + TS - 1) / TS;  // 391

    // layer 0: 128 -> 128
    k_selfloop<128, 128><<<dim3(RB, 1), 256, 0, stream>>>(h0, Wl0, b0, bufB);
    k_edge<128, 128><<<dim3(NTILES, 1), 256, 0, stream>>>(h0, Wr0, src, dst, sorted, boff, tstart, bufB);
    k_relu<<<2048, 256, 0, stream>>>(bufB, bufA, NN * 128);

    // layer 1: 128 -> 256
    k_selfloop<128, 256><<<dim3(RB, 2), 256, 0, stream>>>(bufA, Wl1, b1, bufB);
    k_edge<128, 256><<<dim3(NTILES, 2), 256, 0, stream>>>(bufA, Wr1, src, dst, sorted, boff, tstart, bufB);
    k_relu<<<2048, 256, 0, stream>>>(bufB, bufA, NN * 256);

    // layer 2: 256 -> 128
    k_selfloop<256, 128><<<dim3(RB, 1), 256, 0, stream>>>(bufA, Wl2, b2, bufB);
    k_edge<256, 128><<<dim3(NTILES, 1), 256, 0, stream>>>(bufA, Wr2, src, dst, sorted, boff, tstart, bufB);
    k_relu<<<2048, 256, 0, stream>>>(bufB, bufA, NN * 128);

    // mean pooling per graph
    k_pool<<<RB, 128, 0, stream>>>(bufA, gid, hg, gcnt);
    k_div<<<64, 256, 0, stream>>>(hg, gcnt);

    // MLP head + softmax
    k_mlp<128, 128, true><<<dim3(NG, 1), 256, 0, stream>>>(hg, Wh0, bh0, mlpA);
    k_mlp<128, 256, true><<<dim3(NG, 1), 256, 0, stream>>>(mlpA, Wh1, bh1, mlpB);
    k_mlp<256, 128, true><<<dim3(NG, 1), 256, 0, stream>>>(mlpB, Wh2, bh2, mlpA);
    k_cls<<<(NG + 63) / 64, 64, 0, stream>>>(mlpA, Wc, bc, out);
}

// Round 2
// 4599.082 us; speedup vs baseline: 1.9646x; 1.9646x over previous
//
#include <hip/hip_runtime.h>

#define NN 50000
#define NE 600000
#define NR 16
#define NG 128
#define TS 128
#define NTILES 4704
#define SCAN_B 512
#define NB_SCAN ((NN + SCAN_B - 1) / SCAN_B)   // 98

// ---------------- init / histograms ----------------

__global__ void k_zero(int* bcnt, int* cursor, int* ncnt, int* ncur, float* hg, float* gcnt) {
    int i = blockIdx.x * 256 + threadIdx.x;
    if (i < NR) { bcnt[i] = 0; cursor[i] = 0; }
    if (i < NN) { ncnt[i] = 0; ncur[i] = 0; }
    if (i < NG * 128) hg[i] = 0.f;
    if (i < NG) gcnt[i] = 0.f;
}

__global__ void k_hist(const int* __restrict__ rel, const int* __restrict__ dst,
                       int* __restrict__ bcnt, int* __restrict__ ncnt) {
    __shared__ int lh[NR];
    if (threadIdx.x < NR) lh[threadIdx.x] = 0;
    __syncthreads();
    for (int e = blockIdx.x * blockDim.x + threadIdx.x; e < NE; e += gridDim.x * blockDim.x) {
        atomicAdd(&lh[rel[e]], 1);
        atomicAdd(&ncnt[dst[e]], 1);
    }
    __syncthreads();
    if (threadIdx.x < NR) atomicAdd(&bcnt[threadIdx.x], lh[threadIdx.x]);
}

__global__ void k_scan_rel(const int* __restrict__ bcnt, int* __restrict__ boff, int* __restrict__ tstart) {
    if (threadIdx.x == 0 && blockIdx.x == 0) {
        int o = 0, t = 0;
        for (int r = 0; r < NR; ++r) {
            boff[r] = o; tstart[r] = t;
            o += bcnt[r];
            t += (bcnt[r] + TS - 1) / TS;
        }
        boff[NR] = o; tstart[NR] = t;
    }
}

// node-count scan (3 phases) -> rowptr[NN+1]
__global__ void k_scan1(const int* __restrict__ ncnt, int* __restrict__ bsum) {
    __shared__ int s[SCAN_B];
    int i = blockIdx.x * SCAN_B + threadIdx.x;
    s[threadIdx.x] = (i < NN) ? ncnt[i] : 0;
    __syncthreads();
    for (int off = SCAN_B / 2; off > 0; off >>= 1) {
        if (threadIdx.x < off) s[threadIdx.x] += s[threadIdx.x + off];
        __syncthreads();
    }
    if (threadIdx.x == 0) bsum[blockIdx.x] = s[0];
}

__global__ void k_scan2(const int* __restrict__ bsum, int* __restrict__ bpref, int* __restrict__ rowptr) {
    if (threadIdx.x == 0 && blockIdx.x == 0) {
        int run = 0;
        for (int b = 0; b < NB_SCAN; ++b) { bpref[b] = run; run += bsum[b]; }
        rowptr[NN] = run;
    }
}

__global__ void k_scan3(const int* __restrict__ ncnt, const int* __restrict__ bpref,
                        int* __restrict__ rowptr) {
    __shared__ int s[SCAN_B];
    int i = blockIdx.x * SCAN_B + threadIdx.x;
    int val = (i < NN) ? ncnt[i] : 0;
    s[threadIdx.x] = val;
    __syncthreads();
    for (int off = 1; off < SCAN_B; off <<= 1) {
        int x = (threadIdx.x >= off) ? s[threadIdx.x - off] : 0;
        __syncthreads();
        s[threadIdx.x] += x;
        __syncthreads();
    }
    if (i < NN) rowptr[i] = bpref[blockIdx.x] + s[threadIdx.x] - val;
}

// scatter: rel-sorted order + dst-sorted position for each rel-sorted slot
__global__ void k_scatter(const int* __restrict__ rel, const int* __restrict__ dst,
                          const int* __restrict__ boff, int* __restrict__ cursor,
                          const int* __restrict__ rowptr, int* __restrict__ ncur,
                          int* __restrict__ sorted, int* __restrict__ dpos) {
    __shared__ int lh[NR];
    const int CH = 4096;
    int e0 = blockIdx.x * CH;
    if (threadIdx.x < NR) lh[threadIdx.x] = 0;
    __syncthreads();
    for (int i = threadIdx.x; i < CH; i += 256) {
        int e = e0 + i;
        if (e < NE) atomicAdd(&lh[rel[e]], 1);
    }
    __syncthreads();
    if (threadIdx.x < NR) {
        int c = lh[threadIdx.x];
        lh[threadIdx.x] = (c > 0) ? atomicAdd(&cursor[threadIdx.x], c) : 0;
    }
    __syncthreads();
    for (int i = threadIdx.x; i < CH; i += 256) {
        int e = e0 + i;
        if (e < NE) {
            int r = rel[e];
            int p = boff[r] + atomicAdd(&lh[r], 1);
            int d = dst[e];
            int pd = rowptr[d] + atomicAdd(&ncur[d], 1);
            sorted[p] = e;
            dpos[p] = pd;
        }
    }
}

// ---------------- self-loop GEMM: agg = h @ W_loop + b (plain store) ----------------

template<int DIN, int DOUT>
__global__ __launch_bounds__(256)
void k_selfloop(const float* __restrict__ h, const float* __restrict__ W,
                const float* __restrict__ bias, float* __restrict__ agg) {
    __shared__ float As[8][TS];
    __shared__ float Bs[8][TS];
    const int tid = threadIdx.x;
    const int row0 = blockIdx.x * TS;
    const int col0 = blockIdx.y * TS;
    const int tm = tid >> 4, tn = tid & 15;
    const int lm = tid >> 1, lk = (tid & 1) * 4;
    const int lbk = tid >> 5, lbn = (tid & 31) * 4;
    float acc[8][8];
#pragma unroll
    for (int i = 0; i < 8; ++i)
#pragma unroll
        for (int j = 0; j < 8; ++j) acc[i][j] = 0.f;
    int arow = row0 + lm; if (arow >= NN) arow = NN - 1;
    for (int k0 = 0; k0 < DIN; k0 += 8) {
        float4 av = *reinterpret_cast<const float4*>(h + (size_t)arow * DIN + k0 + lk);
        float4 bv = *reinterpret_cast<const float4*>(W + (size_t)(k0 + lbk) * DOUT + col0 + lbn);
        __syncthreads();
        As[lk + 0][lm] = av.x;
        As[lk + 1][lm] = av.y;
        As[lk + 2][lm] = av.z;
        As[lk + 3][lm] = av.w;
        *reinterpret_cast<float4*>(&Bs[lbk][lbn]) = bv;
        __syncthreads();
#pragma unroll
        for (int k = 0; k < 8; ++k) {
            float a[8], b[8];
            *reinterpret_cast<float4*>(&a[0]) = *reinterpret_cast<const float4*>(&As[k][tm * 4]);
            *reinterpret_cast<float4*>(&a[4]) = *reinterpret_cast<const float4*>(&As[k][64 + tm * 4]);
            *reinterpret_cast<float4*>(&b[0]) = *reinterpret_cast<const float4*>(&Bs[k][tn * 4]);
            *reinterpret_cast<float4*>(&b[4]) = *reinterpret_cast<const float4*>(&Bs[k][64 + tn * 4]);
#pragma unroll
            for (int i = 0; i < 8; ++i)
#pragma unroll
                for (int j = 0; j < 8; ++j) acc[i][j] += a[i] * b[j];
        }
    }
    float4 bl, bh;
    bl = *reinterpret_cast<const float4*>(bias + col0 + tn * 4);
    bh = *reinterpret_cast<const float4*>(bias + col0 + 64 + tn * 4);
#pragma unroll
    for (int i = 0; i < 8; ++i) {
        int m = (i < 4) ? (tm * 4 + i) : (64 + tm * 4 + i - 4);
        int r = row0 + m;
        if (r < NN) {
            float4 v0 = { acc[i][0] + bl.x, acc[i][1] + bl.y, acc[i][2] + bl.z, acc[i][3] + bl.w };
            float4 v1 = { acc[i][4] + bh.x, acc[i][5] + bh.y, acc[i][6] + bh.z, acc[i][7] + bh.w };
            *reinterpret_cast<float4*>(agg + (size_t)r * DOUT + col0 + tn * 4) = v0;
            *reinterpret_cast<float4*>(agg + (size_t)r * DOUT + col0 + 64 + tn * 4) = v1;
        }
    }
}

// ---------------- edge GEMM -> plain msg store at dst-sorted position ----------------

template<int DIN>
__global__ __launch_bounds__(256)
void k_edge_msg(const float* __restrict__ h, const float* __restrict__ Wrel, int ldw, int wbase,
                const int* __restrict__ src,
                const int* __restrict__ sorted, const int* __restrict__ dpos,
                const int* __restrict__ boff, const int* __restrict__ tstart,
                float* __restrict__ msg, int msgw) {
    const int b = blockIdx.x;
    if (b >= tstart[NR]) return;
    int r = 0;
    for (int q = 1; q < NR; ++q) r += (b >= tstart[q]) ? 1 : 0;
    const int e0 = boff[r] + (b - tstart[r]) * TS;
    int cnt = boff[r + 1] - e0;
    if (cnt > TS) cnt = TS;

    __shared__ float As[8][TS];
    __shared__ float Bs[8][TS];
    __shared__ int s_src[TS], s_out[TS];
    const int tid = threadIdx.x;
    if (tid < TS) {
        int ei = e0 + tid; if (ei >= NE) ei = NE - 1;
        int e = sorted[ei];
        s_src[tid] = src[e];
        s_out[tid] = dpos[ei];
    }
    __syncthreads();

    const float* W = Wrel + (size_t)r * DIN * ldw;
    const int mcol0 = blockIdx.y * TS;
    const int wcol0 = wbase + mcol0;
    const int tm = tid >> 4, tn = tid & 15;
    const int lm = tid >> 1, lk = (tid & 1) * 4;
    const int lbk = tid >> 5, lbn = (tid & 31) * 4;
    const int arow = s_src[lm];
    float acc[8][8];
#pragma unroll
    for (int i = 0; i < 8; ++i)
#pragma unroll
        for (int j = 0; j < 8; ++j) acc[i][j] = 0.f;

    for (int k0 = 0; k0 < DIN; k0 += 8) {
        float4 av = *reinterpret_cast<const float4*>(h + (size_t)arow * DIN + k0 + lk);
        float4 bv = *reinterpret_cast<const float4*>(W + (size_t)(k0 + lbk) * ldw + wcol0 + lbn);
        __syncthreads();
        As[lk + 0][lm] = av.x;
        As[lk + 1][lm] = av.y;
        As[lk + 2][lm] = av.z;
        As[lk + 3][lm] = av.w;
        *reinterpret_cast<float4*>(&Bs[lbk][lbn]) = bv;
        __syncthreads();
#pragma unroll
        for (int k = 0; k < 8; ++k) {
            float a[8], bb[8];
            *reinterpret_cast<float4*>(&a[0]) = *reinterpret_cast<const float4*>(&As[k][tm * 4]);
            *reinterpret_cast<float4*>(&a[4]) = *reinterpret_cast<const float4*>(&As[k][64 + tm * 4]);
            *reinterpret_cast<float4*>(&bb[0]) = *reinterpret_cast<const float4*>(&Bs[k][tn * 4]);
            *reinterpret_cast<float4*>(&bb[4]) = *reinterpret_cast<const float4*>(&Bs[k][64 + tn * 4]);
#pragma unroll
            for (int i = 0; i < 8; ++i)
#pragma unroll
                for (int j = 0; j < 8; ++j) acc[i][j] += a[i] * bb[j];
        }
    }
#pragma unroll
    for (int i = 0; i < 8; ++i) {
        int m = (i < 4) ? (tm * 4 + i) : (64 + tm * 4 + i - 4);
        if (m < cnt) {
            float* dp = msg + (size_t)s_out[m] * msgw + mcol0;
            float4 v0 = { acc[i][0], acc[i][1], acc[i][2], acc[i][3] };
            float4 v1 = { acc[i][4], acc[i][5], acc[i][6], acc[i][7] };
            *reinterpret_cast<float4*>(dp + tn * 4) = v0;
            *reinterpret_cast<float4*>(dp + 64 + tn * 4) = v1;
        }
    }
}

// segmented reduce over dst-sorted msg rows + self-loop + relu
__global__ void k_reduce(const float* __restrict__ msg, int msgw,
                         const float* __restrict__ self, int ncf, int coloff,
                         const int* __restrict__ rowptr, float* __restrict__ out) {
    int n = blockIdx.x, c = threadIdx.x;
    float acc = self[(size_t)n * ncf + coloff + c];
    int j1 = rowptr[n + 1];
    for (int j = rowptr[n]; j < j1; ++j) acc += msg[(size_t)j * msgw + c];
    out[(size_t)n * ncf + coloff + c] = acc > 0.f ? acc : 0.f;
}

// ---------------- atomic fallback (only if ws_size too small) ----------------

template<int DIN, int DOUT>
__global__ __launch_bounds__(256)
void k_edge_atomic(const float* __restrict__ h, const float* __restrict__ Wrel,
                   const int* __restrict__ src, const int* __restrict__ dst,
                   const int* __restrict__ sorted, const int* __restrict__ boff,
                   const int* __restrict__ tstart, float* __restrict__ agg) {
    const int b = blockIdx.x;
    if (b >= tstart[NR]) return;
    int r = 0;
    for (int q = 1; q < NR; ++q) r += (b >= tstart[q]) ? 1 : 0;
    const int e0 = boff[r] + (b - tstart[r]) * TS;
    int cnt = boff[r + 1] - e0;
    if (cnt > TS) cnt = TS;

    __shared__ float As[8][TS];
    __shared__ float Bs[8][TS];
    __shared__ int s_src[TS], s_dst[TS];
    const int tid = threadIdx.x;
    if (tid < TS) {
        int ei = e0 + tid; if (ei >= NE) ei = NE - 1;
        int e = sorted[ei];
        s_src[tid] = src[e];
        s_dst[tid] = dst[e];
    }
    __syncthreads();
    const float* W = Wrel + (size_t)r * DIN * DOUT;
    const int col0 = blockIdx.y * TS;
    const int tm = tid >> 4, tn = tid & 15;
    const int lm = tid >> 1, lk = (tid & 1) * 4;
    const int lbk = tid >> 5, lbn = (tid & 31) * 4;
    const int arow = s_src[lm];
    float acc[8][8];
#pragma unroll
    for (int i = 0; i < 8; ++i)
#pragma unroll
        for (int j = 0; j < 8; ++j) acc[i][j] = 0.f;
    for (int k0 = 0; k0 < DIN; k0 += 8) {
        float4 av = *reinterpret_cast<const float4*>(h + (size_t)arow * DIN + k0 + lk);
        float4 bv = *reinterpret_cast<const float4*>(W + (size_t)(k0 + lbk) * DOUT + col0 + lbn);
        __syncthreads();
        As[lk + 0][lm] = av.x;
        As[lk + 1][lm] = av.y;
        As[lk + 2][lm] = av.z;
        As[lk + 3][lm] = av.w;
        *reinterpret_cast<float4*>(&Bs[lbk][lbn]) = bv;
        __syncthreads();
#pragma unroll
        for (int k = 0; k < 8; ++k) {
            float a[8], bb[8];
            *reinterpret_cast<float4*>(&a[0]) = *reinterpret_cast<const float4*>(&As[k][tm * 4]);
            *reinterpret_cast<float4*>(&a[4]) = *reinterpret_cast<const float4*>(&As[k][64 + tm * 4]);
            *reinterpret_cast<float4*>(&bb[0]) = *reinterpret_cast<const float4*>(&Bs[k][tn * 4]);
            *reinterpret_cast<float4*>(&bb[4]) = *reinterpret_cast<const float4*>(&Bs[k][64 + tn * 4]);
#pragma unroll
            for (int i = 0; i < 8; ++i)
#pragma unroll
                for (int j = 0; j < 8; ++j) acc[i][j] += a[i] * bb[j];
        }
    }
#pragma unroll
    for (int i = 0; i < 8; ++i) {
        int m = (i < 4) ? (tm * 4 + i) : (64 + tm * 4 + i - 4);
        if (m < cnt) {
            int dn = s_dst[m];
#pragma unroll
            for (int j = 0; j < 4; ++j) {
                atomicAdd(&agg[(size_t)dn * DOUT + col0 + tn * 4 + j], acc[i][j]);
                atomicAdd(&agg[(size_t)dn * DOUT + col0 + 64 + tn * 4 + j], acc[i][4 + j]);
            }
        }
    }
}

__global__ void k_relu(const float* __restrict__ in, float* __restrict__ out, int n) {
    for (int i = blockIdx.x * blockDim.x + threadIdx.x; i < n; i += gridDim.x * blockDim.x) {
        float v = in[i];
        out[i] = v > 0.f ? v : 0.f;
    }
}

// ---------------- pooling / MLP ----------------

__global__ void k_pool(const float* __restrict__ h, const int* __restrict__ gid,
                       float* __restrict__ hg, float* __restrict__ gcnt) {
    const int c = threadIdx.x;
    int n0 = blockIdx.x * 128;
    if (n0 >= NN) return;
    int cur = gid[n0];
    float run = 0.f, crun = 0.f;
    for (int i = 0; i < 128; ++i) {
        int n = n0 + i;
        if (n >= NN) break;
        int g = gid[n];
        if (g != cur) {
            atomicAdd(&hg[cur * 128 + c], run);
            if (c == 0) atomicAdd(&gcnt[cur], crun);
            run = 0.f; crun = 0.f; cur = g;
        }
        run += h[(size_t)n * 128 + c];
        crun += 1.f;
    }
    atomicAdd(&hg[cur * 128 + c], run);
    if (c == 0) atomicAdd(&gcnt[cur], crun);
}

__global__ void k_div(float* hg, const float* __restrict__ gcnt) {
    int i = blockIdx.x * 256 + threadIdx.x;
    if (i < NG * 128) {
        int g = i >> 7;
        float c = gcnt[g];
        hg[i] /= (c > 1.f ? c : 1.f);
    }
}

template<int DIN, int DOUT, bool RELU>
__global__ void k_mlp(const float* __restrict__ in, const float* __restrict__ W,
                      const float* __restrict__ bias, float* __restrict__ out) {
    int g = blockIdx.x;
    int c = blockIdx.y * 256 + threadIdx.x;
    if (c >= DOUT) return;
    float acc = bias[c];
    for (int k = 0; k < DIN; ++k) acc += in[g * DIN + k] * W[k * DOUT + c];
    if (RELU) acc = acc > 0.f ? acc : 0.f;
    out[g * DOUT + c] = acc;
}

__global__ void k_cls(const float* __restrict__ in, const float* __restrict__ Wc,
                      const float* __restrict__ bc, float* __restrict__ out) {
    int g = blockIdx.x * blockDim.x + threadIdx.x;
    if (g >= NG) return;
    float logit[8];
#pragma unroll
    for (int c = 0; c < 8; ++c) logit[c] = bc[c];
    for (int k = 0; k < 128; ++k) {
        float v = in[g * 128 + k];
#pragma unroll
        for (int c = 0; c < 8; ++c) logit[c] += v * Wc[k * 8 + c];
    }
    float m = logit[0];
#pragma unroll
    for (int c = 1; c < 8; ++c) m = logit[c] > m ? logit[c] : m;
    float s = 0.f;
    float e[8];
#pragma unroll
    for (int c = 0; c < 8; ++c) { e[c] = expf(logit[c] - m); s += e[c]; }
    float inv = 1.f / s;
#pragma unroll
    for (int c = 0; c < 8; ++c) out[g * 8 + c] = e[c] * inv;
}

// ---------------- launcher ----------------

extern "C" void kernel_launch(void* const* d_in, const int* in_sizes, int n_in,
                              void* d_out, int out_size, void* d_ws, size_t ws_size,
                              hipStream_t stream) {
    const float* h0   = (const float*)d_in[0];
    const int* src    = (const int*)d_in[1];
    const int* dst    = (const int*)d_in[2];
    const int* rel    = (const int*)d_in[3];
    const int* gid    = (const int*)d_in[4];
    const float* Wr0  = (const float*)d_in[5];
    const float* Wl0  = (const float*)d_in[6];
    const float* b0   = (const float*)d_in[7];
    const float* Wr1  = (const float*)d_in[8];
    const float* Wl1  = (const float*)d_in[9];
    const float* b1   = (const float*)d_in[10];
    const float* Wr2  = (const float*)d_in[11];
    const float* Wl2  = (const float*)d_in[12];
    const float* b2   = (const float*)d_in[13];
    const float* Wh0  = (const float*)d_in[14];
    const float* bh0  = (const float*)d_in[15];
    const float* Wh1  = (const float*)d_in[16];
    const float* bh1  = (const float*)d_in[17];
    const float* Wh2  = (const float*)d_in[18];
    const float* bh2  = (const float*)d_in[19];
    const float* Wc   = (const float*)d_in[20];
    const float* bc   = (const float*)d_in[21];
    float* out = (float*)d_out;

    // workspace layout
    char* p = (char*)d_ws;
    float* bufA  = (float*)p;            p += (size_t)NN * 256 * 4;
    float* bufB  = (float*)p;            p += (size_t)NN * 256 * 4;
    int* sorted  = (int*)p;              p += (size_t)NE * 4;
    int* dpos    = (int*)p;              p += (size_t)NE * 4;
    int* bcnt    = (int*)p;              p += NR * 4;
    int* boff    = (int*)p;              p += (NR + 1) * 4;
    int* tstart  = (int*)p;              p += (NR + 1) * 4;
    int* cursor  = (int*)p;              p += NR * 4;
    int* ncnt    = (int*)p;              p += (size_t)NN * 4;
    int* ncur    = (int*)p;              p += (size_t)NN * 4;
    int* rowptr  = (int*)p;              p += (size_t)(NN + 1) * 4;
    int* bsum    = (int*)p;              p += NB_SCAN * 4;
    int* bpref   = (int*)p;              p += NB_SCAN * 4;
    float* hg    = (float*)p;            p += (size_t)NG * 128 * 4;
    float* gcnt  = (float*)p;            p += NG * 4;
    float* mlpA  = (float*)p;            p += (size_t)NG * 256 * 4;
    float* mlpB  = (float*)p;            p += (size_t)NG * 256 * 4;
    // align msg to 256B
    p = (char*)(((uintptr_t)p + 255) & ~(uintptr_t)255);
    float* msg   = (float*)p;
    size_t base  = (size_t)(p - (char*)d_ws);
    size_t need_full = base + (size_t)NE * 256 * 4;
    size_t need_half = base + (size_t)NE * 128 * 4;
    int mode = (ws_size >= need_full) ? 2 : (ws_size >= need_half ? 1 : 0);

    // preprocessing: rel counting sort + dst CSR + dst positions
    k_zero<<<(NN + 255) / 256, 256, 0, stream>>>(bcnt, cursor, ncnt, ncur, hg, gcnt);
    k_hist<<<256, 256, 0, stream>>>(rel, dst, bcnt, ncnt);
    k_scan_rel<<<1, 64, 0, stream>>>(bcnt, boff, tstart);
    k_scan1<<<NB_SCAN, SCAN_B, 0, stream>>>(ncnt, bsum);
    k_scan2<<<1, 64, 0, stream>>>(bsum, bpref, rowptr);
    k_scan3<<<NB_SCAN, SCAN_B, 0, stream>>>(ncnt, bpref, rowptr);
    k_scatter<<<(NE + 4095) / 4096, 256, 0, stream>>>(rel, dst, boff, cursor, rowptr, ncur, sorted, dpos);

    const int RB = (NN + TS - 1) / TS;  // 391

    if (mode >= 1) {
        // layer 0: 128 -> 128
        k_selfloop<128, 128><<<dim3(RB, 1), 256, 0, stream>>>(h0, Wl0, b0, bufB);
        k_edge_msg<128><<<dim3(NTILES, 1), 256, 0, stream>>>(h0, Wr0, 128, 0, src, sorted, dpos, boff, tstart, msg, 128);
        k_reduce<<<NN, 128, 0, stream>>>(msg, 128, bufB, 128, 0, rowptr, bufA);

        // layer 1: 128 -> 256
        k_selfloop<128, 256><<<dim3(RB, 2), 256, 0, stream>>>(bufA, Wl1, b1, bufB);
        if (mode == 2) {
            k_edge_msg<128><<<dim3(NTILES, 2), 256, 0, stream>>>(bufA, Wr1, 256, 0, src, sorted, dpos, boff, tstart, msg, 256);
            k_reduce<<<NN, 256, 0, stream>>>(msg, 256, bufB, 256, 0, rowptr, bufA);
        } else {
            k_edge_msg<128><<<dim3(NTILES, 1), 256, 0, stream>>>(bufA, Wr1, 256, 0, src, sorted, dpos, boff, tstart, msg, 128);
            k_reduce<<<NN, 128, 0, stream>>>(msg, 128, bufB, 256, 0, rowptr, bufA);
            k_edge_msg<128><<<dim3(NTILES, 1), 256, 0, stream>>>(bufA, Wr1, 256, 128, src, sorted, dpos, boff, tstart, msg, 128);
            k_reduce<<<NN, 128, 0, stream>>>(msg, 128, bufB, 256, 128, rowptr, bufA);
        }

        // layer 2: 256 -> 128
        k_selfloop<256, 128><<<dim3(RB, 1), 256, 0, stream>>>(bufA, Wl2, b2, bufB);
        k_edge_msg<256><<<dim3(NTILES, 1), 256, 0, stream>>>(bufA, Wr2, 128, 0, src, sorted, dpos, boff, tstart, msg, 128);
        k_reduce<<<NN, 128, 0, stream>>>(msg, 128, bufB, 128, 0, rowptr, bufA);
    } else {
        // atomic fallback
        k_selfloop<128, 128><<<dim3(RB, 1), 256, 0, stream>>>(h0, Wl0, b0, bufB);
        k_edge_atomic<128, 128><<<dim3(NTILES, 1), 256, 0, stream>>>(h0, Wr0, src, dst, sorted, boff, tstart, bufB);
        k_relu<<<2048, 256, 0, stream>>>(bufB, bufA, NN * 128);
        k_selfloop<128, 256><<<dim3(RB, 2), 256, 0, stream>>>(bufA, Wl1, b1, bufB);
        k_edge_atomic<128, 256><<<dim3(NTILES, 2), 256, 0, stream>>>(bufA, Wr1, src, dst, sorted, boff, tstart, bufB);
        k_relu<<<2048, 256, 0, stream>>>(bufB, bufA, NN * 256);
        k_selfloop<256, 128><<<dim3(RB, 1), 256, 0, stream>>>(bufA, Wl2, b2, bufB);
        k_edge_atomic<256, 128><<<dim3(NTILES, 1), 256, 0, stream>>>(bufA, Wr2, src, dst, sorted, boff, tstart, bufB);
        k_relu<<<2048, 256, 0, stream>>>(bufB, bufA, NN * 128);
    }

    // mean pooling per graph
    k_pool<<<RB, 128, 0, stream>>>(bufA, gid, hg, gcnt);
    k_div<<<64, 256, 0, stream>>>(hg, gcnt);

    // MLP head + softmax
    k_mlp<128, 128, true><<<dim3(NG, 1), 256, 0, stream>>>(hg, Wh0, bh0, mlpA);
    k_mlp<128, 256, true><<<dim3(NG, 1), 256, 0, stream>>>(mlpA, Wh1, bh1, mlpB);
    k_mlp<256, 128, true><<<dim3(NG, 1), 256, 0, stream>>>(mlpB, Wh2, bh2, mlpA);
    k_cls<<<(NG + 63) / 64, 64, 0, stream>>>(mlpA, Wc, bc, out);
}

// Round 3
// 1810.571 us; speedup vs baseline: 4.9904x; 2.5401x over previous
//
#include <hip/hip_runtime.h>
#include <stdint.h>

#define NN 50000
#define NE 600000
#define NR 16
#define NG 128
#define TS 128
#define SCAN_B 512
#define NB_SCAN ((NN + SCAN_B - 1) / SCAN_B)   // 98
#define MAXB 1024

static __device__ __forceinline__ unsigned short f2bf(float x) {
    unsigned int b = __float_as_uint(x);
    b += 0x7FFFu + ((b >> 16) & 1u);
    return (unsigned short)(b >> 16);
}
static __device__ __forceinline__ float bf2f(unsigned short u) {
    return __uint_as_float(((unsigned int)u) << 16);
}

// ---------------- init / histograms ----------------

__global__ void k_zero(int* bcnt, int* cursor, int* ncnt, int* ncur, float* hg, float* gcnt) {
    int i = blockIdx.x * 256 + threadIdx.x;
    if (i < MAXB) { bcnt[i] = 0; cursor[i] = 0; }
    if (i < NN) { ncnt[i] = 0; ncur[i] = 0; }
    if (i < NG * 128) hg[i] = 0.f;
    if (i < NG) gcnt[i] = 0.f;
}

// bucket key = (dst/npc)*NR + rel
__global__ void k_hist(const int* __restrict__ rel, const int* __restrict__ dst,
                       int* __restrict__ bcnt, int* __restrict__ ncnt, int npc, int B) {
    __shared__ int lh[MAXB];
    for (int i = threadIdx.x; i < B; i += 256) lh[i] = 0;
    __syncthreads();
    for (int e = blockIdx.x * blockDim.x + threadIdx.x; e < NE; e += gridDim.x * blockDim.x) {
        int d = dst[e];
        atomicAdd(&lh[(d / npc) * NR + rel[e]], 1);
        atomicAdd(&ncnt[d], 1);
    }
    __syncthreads();
    for (int i = threadIdx.x; i < B; i += 256) atomicAdd(&bcnt[i], lh[i]);
}

// parallel exclusive scan of bucket counts (and tile counts) — B <= 1024
__global__ void k_scan_buckets(const int* __restrict__ bcnt, int B,
                               int* __restrict__ boff, int* __restrict__ tstart) {
    __shared__ int s1[MAXB], s2[MAXB];
    int tid = threadIdx.x;
    int v1 = (tid < B) ? bcnt[tid] : 0;
    int v2 = (v1 + TS - 1) / TS;
    s1[tid] = v1; s2[tid] = v2;
    __syncthreads();
    for (int off = 1; off < MAXB; off <<= 1) {
        int a1 = (tid >= off) ? s1[tid - off] : 0;
        int a2 = (tid >= off) ? s2[tid - off] : 0;
        __syncthreads();
        s1[tid] += a1; s2[tid] += a2;
        __syncthreads();
    }
    if (tid < B) {
        boff[tid] = s1[tid] - v1;
        tstart[tid] = s2[tid] - v2;
        if (tid == B - 1) { boff[B] = s1[tid]; tstart[B] = s2[tid]; }
    }
}

// node-count scan (3 phases) -> rowptr[NN+1]
__global__ void k_scan1(const int* __restrict__ ncnt, int* __restrict__ bsum) {
    __shared__ int s[SCAN_B];
    int i = blockIdx.x * SCAN_B + threadIdx.x;
    s[threadIdx.x] = (i < NN) ? ncnt[i] : 0;
    __syncthreads();
    for (int off = SCAN_B / 2; off > 0; off >>= 1) {
        if (threadIdx.x < off) s[threadIdx.x] += s[threadIdx.x + off];
        __syncthreads();
    }
    if (threadIdx.x == 0) bsum[blockIdx.x] = s[0];
}

__global__ void k_scan2(const int* __restrict__ bsum, int* __restrict__ bpref, int* __restrict__ rowptr) {
    if (threadIdx.x == 0 && blockIdx.x == 0) {
        int run = 0;
        for (int b = 0; b < NB_SCAN; ++b) { bpref[b] = run; run += bsum[b]; }
        rowptr[NN] = run;
    }
}

__global__ void k_scan3(const int* __restrict__ ncnt, const int* __restrict__ bpref,
                        int* __restrict__ rowptr) {
    __shared__ int s[SCAN_B];
    int i = blockIdx.x * SCAN_B + threadIdx.x;
    int val = (i < NN) ? ncnt[i] : 0;
    s[threadIdx.x] = val;
    __syncthreads();
    for (int off = 1; off < SCAN_B; off <<= 1) {
        int x = (threadIdx.x >= off) ? s[threadIdx.x - off] : 0;
        __syncthreads();
        s[threadIdx.x] += x;
        __syncthreads();
    }
    if (i < NN) rowptr[i] = bpref[blockIdx.x] + s[threadIdx.x] - val;
}

// scatter edges into (chunk,rel)-bucket order; record global dst-sorted position
__global__ void k_scatter(const int* __restrict__ rel, const int* __restrict__ dst,
                          const int* __restrict__ boff, int* __restrict__ cursor,
                          const int* __restrict__ rowptr, int* __restrict__ ncur,
                          int* __restrict__ sorted, int* __restrict__ dpos, int npc, int B) {
    __shared__ int lh[MAXB];
    const int CH = 4096;
    int e0 = blockIdx.x * CH;
    for (int i = threadIdx.x; i < B; i += 256) lh[i] = 0;
    __syncthreads();
    for (int i = threadIdx.x; i < CH; i += 256) {
        int e = e0 + i;
        if (e < NE) atomicAdd(&lh[(dst[e] / npc) * NR + rel[e]], 1);
    }
    __syncthreads();
    for (int i = threadIdx.x; i < B; i += 256) {
        int c = lh[i];
        lh[i] = (c > 0) ? atomicAdd(&cursor[i], c) : 0;
    }
    __syncthreads();
    for (int i = threadIdx.x; i < CH; i += 256) {
        int e = e0 + i;
        if (e < NE) {
            int d = dst[e];
            int b = (d / npc) * NR + rel[e];
            int p = boff[b] + atomicAdd(&lh[b], 1);
            int pd = rowptr[d] + atomicAdd(&ncur[d], 1);
            sorted[p] = e;
            dpos[p] = pd;
        }
    }
}

// ---------------- self-loop GEMM: out = h @ W_loop + b ----------------

template<int DIN, int DOUT>
__global__ __launch_bounds__(256)
void k_selfloop(const float* __restrict__ h, const float* __restrict__ W,
                const float* __restrict__ bias, float* __restrict__ agg) {
    __shared__ float As[8][TS];
    __shared__ float Bs[8][TS];
    const int tid = threadIdx.x;
    const int row0 = blockIdx.x * TS;
    const int col0 = blockIdx.y * TS;
    const int tm = tid >> 4, tn = tid & 15;
    const int lm = tid >> 1, lk = (tid & 1) * 4;
    const int lbk = tid >> 5, lbn = (tid & 31) * 4;
    float acc[8][8];
#pragma unroll
    for (int i = 0; i < 8; ++i)
#pragma unroll
        for (int j = 0; j < 8; ++j) acc[i][j] = 0.f;
    int arow = row0 + lm; if (arow >= NN) arow = NN - 1;
    for (int k0 = 0; k0 < DIN; k0 += 8) {
        float4 av = *reinterpret_cast<const float4*>(h + (size_t)arow * DIN + k0 + lk);
        float4 bv = *reinterpret_cast<const float4*>(W + (size_t)(k0 + lbk) * DOUT + col0 + lbn);
        __syncthreads();
        As[lk + 0][lm] = av.x;
        As[lk + 1][lm] = av.y;
        As[lk + 2][lm] = av.z;
        As[lk + 3][lm] = av.w;
        *reinterpret_cast<float4*>(&Bs[lbk][lbn]) = bv;
        __syncthreads();
#pragma unroll
        for (int k = 0; k < 8; ++k) {
            float a[8], b[8];
            *reinterpret_cast<float4*>(&a[0]) = *reinterpret_cast<const float4*>(&As[k][tm * 4]);
            *reinterpret_cast<float4*>(&a[4]) = *reinterpret_cast<const float4*>(&As[k][64 + tm * 4]);
            *reinterpret_cast<float4*>(&b[0]) = *reinterpret_cast<const float4*>(&Bs[k][tn * 4]);
            *reinterpret_cast<float4*>(&b[4]) = *reinterpret_cast<const float4*>(&Bs[k][64 + tn * 4]);
#pragma unroll
            for (int i = 0; i < 8; ++i)
#pragma unroll
                for (int j = 0; j < 8; ++j) acc[i][j] += a[i] * b[j];
        }
    }
    float4 bl = *reinterpret_cast<const float4*>(bias + col0 + tn * 4);
    float4 bh = *reinterpret_cast<const float4*>(bias + col0 + 64 + tn * 4);
#pragma unroll
    for (int i = 0; i < 8; ++i) {
        int m = (i < 4) ? (tm * 4 + i) : (64 + tm * 4 + i - 4);
        int r = row0 + m;
        if (r < NN) {
            float4 v0 = { acc[i][0] + bl.x, acc[i][1] + bl.y, acc[i][2] + bl.z, acc[i][3] + bl.w };
            float4 v1 = { acc[i][4] + bh.x, acc[i][5] + bh.y, acc[i][6] + bh.z, acc[i][7] + bh.w };
            *reinterpret_cast<float4*>(agg + (size_t)r * DOUT + col0 + tn * 4) = v0;
            *reinterpret_cast<float4*>(agg + (size_t)r * DOUT + col0 + 64 + tn * 4) = v1;
        }
    }
}

// ---------------- per-chunk edge GEMM -> bf16 msg rows (always 128 cols/pass) ----------------

template<int DIN>
__global__ __launch_bounds__(256)
void k_edge_msg(const float* __restrict__ h, const float* __restrict__ Wrel, int ldw, int wbase,
                const int* __restrict__ src,
                const int* __restrict__ sorted, const int* __restrict__ dpos,
                const int* __restrict__ boff, const int* __restrict__ tstart,
                const int* __restrict__ rowptr,
                unsigned short* __restrict__ msg, int chunk, int n0, int capRows) {
    const int tb0 = tstart[chunk * NR];
    const int tend = tstart[(chunk + 1) * NR];
    const int t = tb0 + blockIdx.x;
    if (t >= tend) return;
    int r = 0;
#pragma unroll
    for (int q = 1; q < NR; ++q) r += (t >= tstart[chunk * NR + q]) ? 1 : 0;
    const int bk = chunk * NR + r;
    const int e0 = boff[bk] + (t - tstart[bk]) * TS;
    int cnt = boff[bk + 1] - e0;
    if (cnt > TS) cnt = TS;

    __shared__ float As[8][TS];
    __shared__ float Bs[8][TS];
    __shared__ int s_src[TS], s_out[TS];
    const int tid = threadIdx.x;
    if (tid < TS) {
        int cES = rowptr[n0];
        int valid = tid < cnt;
        int ei = e0 + (valid ? tid : 0);
        int e = sorted[ei];
        s_src[tid] = src[e];
        int row = dpos[ei] - cES;
        s_out[tid] = (valid && row < capRows) ? row : -1;
    }
    __syncthreads();

    const float* W = Wrel + (size_t)r * DIN * ldw + wbase;
    const int tm = tid >> 4, tn = tid & 15;
    const int lm = tid >> 1, lk = (tid & 1) * 4;
    const int lbk = tid >> 5, lbn = (tid & 31) * 4;
    const int arow = s_src[lm];
    float acc[8][8];
#pragma unroll
    for (int i = 0; i < 8; ++i)
#pragma unroll
        for (int j = 0; j < 8; ++j) acc[i][j] = 0.f;

    for (int k0 = 0; k0 < DIN; k0 += 8) {
        float4 av = *reinterpret_cast<const float4*>(h + (size_t)arow * DIN + k0 + lk);
        float4 bv = *reinterpret_cast<const float4*>(W + (size_t)(k0 + lbk) * ldw + lbn);
        __syncthreads();
        As[lk + 0][lm] = av.x;
        As[lk + 1][lm] = av.y;
        As[lk + 2][lm] = av.z;
        As[lk + 3][lm] = av.w;
        *reinterpret_cast<float4*>(&Bs[lbk][lbn]) = bv;
        __syncthreads();
#pragma unroll
        for (int k = 0; k < 8; ++k) {
            float a[8], bb[8];
            *reinterpret_cast<float4*>(&a[0]) = *reinterpret_cast<const float4*>(&As[k][tm * 4]);
            *reinterpret_cast<float4*>(&a[4]) = *reinterpret_cast<const float4*>(&As[k][64 + tm * 4]);
            *reinterpret_cast<float4*>(&bb[0]) = *reinterpret_cast<const float4*>(&Bs[k][tn * 4]);
            *reinterpret_cast<float4*>(&bb[4]) = *reinterpret_cast<const float4*>(&Bs[k][64 + tn * 4]);
#pragma unroll
            for (int i = 0; i < 8; ++i)
#pragma unroll
                for (int j = 0; j < 8; ++j) acc[i][j] += a[i] * bb[j];
        }
    }
#pragma unroll
    for (int i = 0; i < 8; ++i) {
        int m = (i < 4) ? (tm * 4 + i) : (64 + tm * 4 + i - 4);
        int o = s_out[m];
        if (o >= 0) {
            unsigned short* dp = msg + (size_t)o * 128;
            ushort4 v0 = { f2bf(acc[i][0]), f2bf(acc[i][1]), f2bf(acc[i][2]), f2bf(acc[i][3]) };
            ushort4 v1 = { f2bf(acc[i][4]), f2bf(acc[i][5]), f2bf(acc[i][6]), f2bf(acc[i][7]) };
            *reinterpret_cast<ushort4*>(dp + tn * 4) = v0;
            *reinterpret_cast<ushort4*>(dp + 64 + tn * 4) = v1;
        }
    }
}

// segmented reduce over in-chunk dst-sorted bf16 msg rows, fold onto self buffer, relu, in place
__global__ void k_reduce(const unsigned short* __restrict__ msg,
                         float* __restrict__ buf, int ncf, int coloff,
                         const int* __restrict__ rowptr, int n0, int capRows) {
    int n = n0 + blockIdx.x;
    if (n >= NN) return;
    int c = threadIdx.x;
    int cES = rowptr[n0];
    float acc = buf[(size_t)n * ncf + coloff + c];
    int j1 = rowptr[n + 1];
    for (int j = rowptr[n]; j < j1; ++j) {
        int rr = j - cES;
        if (rr >= capRows) break;
        acc += bf2f(msg[(size_t)rr * 128 + c]);
    }
    buf[(size_t)n * ncf + coloff + c] = acc > 0.f ? acc : 0.f;
}

// ---------------- pooling / MLP ----------------

__global__ void k_pool(const float* __restrict__ h, const int* __restrict__ gid,
                       float* __restrict__ hg, float* __restrict__ gcnt) {
    const int c = threadIdx.x;
    int n0 = blockIdx.x * 128;
    if (n0 >= NN) return;
    int cur = gid[n0];
    float run = 0.f, crun = 0.f;
    for (int i = 0; i < 128; ++i) {
        int n = n0 + i;
        if (n >= NN) break;
        int g = gid[n];
        if (g != cur) {
            atomicAdd(&hg[cur * 128 + c], run);
            if (c == 0) atomicAdd(&gcnt[cur], crun);
            run = 0.f; crun = 0.f; cur = g;
        }
        run += h[(size_t)n * 128 + c];
        crun += 1.f;
    }
    atomicAdd(&hg[cur * 128 + c], run);
    if (c == 0) atomicAdd(&gcnt[cur], crun);
}

__global__ void k_div(float* hg, const float* __restrict__ gcnt) {
    int i = blockIdx.x * 256 + threadIdx.x;
    if (i < NG * 128) {
        int g = i >> 7;
        float c = gcnt[g];
        hg[i] /= (c > 1.f ? c : 1.f);
    }
}

template<int DIN, int DOUT, bool RELU>
__global__ void k_mlp(const float* __restrict__ in, const float* __restrict__ W,
                      const float* __restrict__ bias, float* __restrict__ out) {
    int g = blockIdx.x;
    int c = blockIdx.y * 256 + threadIdx.x;
    if (c >= DOUT) return;
    float acc = bias[c];
    for (int k = 0; k < DIN; ++k) acc += in[g * DIN + k] * W[k * DOUT + c];
    if (RELU) acc = acc > 0.f ? acc : 0.f;
    out[g * DOUT + c] = acc;
}

__global__ void k_cls(const float* __restrict__ in, const float* __restrict__ Wc,
                      const float* __restrict__ bc, float* __restrict__ out) {
    int g = blockIdx.x * blockDim.x + threadIdx.x;
    if (g >= NG) return;
    float logit[8];
#pragma unroll
    for (int c = 0; c < 8; ++c) logit[c] = bc[c];
    for (int k = 0; k < 128; ++k) {
        float v = in[g * 128 + k];
#pragma unroll
        for (int c = 0; c < 8; ++c) logit[c] += v * Wc[k * 8 + c];
    }
    float m = logit[0];
#pragma unroll
    for (int c = 1; c < 8; ++c) m = logit[c] > m ? logit[c] : m;
    float s = 0.f;
    float e[8];
#pragma unroll
    for (int c = 0; c < 8; ++c) { e[c] = expf(logit[c] - m); s += e[c]; }
    float inv = 1.f / s;
#pragma unroll
    for (int c = 0; c < 8; ++c) out[g * 8 + c] = e[c] * inv;
}

// ---------------- launcher ----------------

extern "C" void kernel_launch(void* const* d_in, const int* in_sizes, int n_in,
                              void* d_out, int out_size, void* d_ws, size_t ws_size,
                              hipStream_t stream) {
    const float* h0   = (const float*)d_in[0];
    const int* src    = (const int*)d_in[1];
    const int* dst    = (const int*)d_in[2];
    const int* rel    = (const int*)d_in[3];
    const int* gid    = (const int*)d_in[4];
    const float* Wr0  = (const float*)d_in[5];
    const float* Wl0  = (const float*)d_in[6];
    const float* b0   = (const float*)d_in[7];
    const float* Wr1  = (const float*)d_in[8];
    const float* Wl1  = (const float*)d_in[9];
    const float* b1   = (const float*)d_in[10];
    const float* Wr2  = (const float*)d_in[11];
    const float* Wl2  = (const float*)d_in[12];
    const float* b2   = (const float*)d_in[13];
    const float* Wh0  = (const float*)d_in[14];
    const float* bh0  = (const float*)d_in[15];
    const float* Wh1  = (const float*)d_in[16];
    const float* bh1  = (const float*)d_in[17];
    const float* Wh2  = (const float*)d_in[18];
    const float* bh2  = (const float*)d_in[19];
    const float* Wc   = (const float*)d_in[20];
    const float* bc   = (const float*)d_in[21];
    float* out = (float*)d_out;

    // workspace layout
    char* p = (char*)d_ws;
    float* bufA  = (float*)p;            p += (size_t)NN * 128 * 4;   // layer 0/2 output
    float* bufB  = (float*)p;            p += (size_t)NN * 256 * 4;   // layer 1 output
    int* sorted  = (int*)p;              p += (size_t)NE * 4;
    int* dpos    = (int*)p;              p += (size_t)NE * 4;
    int* ncnt    = (int*)p;              p += (size_t)NN * 4;
    int* ncur    = (int*)p;              p += (size_t)NN * 4;
    int* rowptr  = (int*)p;              p += (size_t)(NN + 1) * 4;
    int* bsum    = (int*)p;              p += NB_SCAN * 4;
    int* bpref   = (int*)p;              p += NB_SCAN * 4;
    int* bcnt    = (int*)p;              p += MAXB * 4;
    int* boff    = (int*)p;              p += (MAXB + 1) * 4;
    int* tstart  = (int*)p;              p += (MAXB + 1) * 4;
    int* cursor  = (int*)p;              p += MAXB * 4;
    float* hg    = (float*)p;            p += (size_t)NG * 128 * 4;
    float* gcnt  = (float*)p;            p += NG * 4;
    float* mlpA  = (float*)p;            p += (size_t)NG * 256 * 4;
    float* mlpB  = (float*)p;            p += (size_t)NG * 256 * 4;
    p = (char*)(((uintptr_t)p + 255) & ~(uintptr_t)255);
    unsigned short* msg = (unsigned short*)p;

    long long avail = (long long)ws_size - (long long)(p - (char*)d_ws);
    if (avail < (1 << 20)) avail = (1 << 20);
    long long capR64 = avail / 256;                 // bf16 rows of 128
    int C = 64;
    for (int c = 1; c <= 64; ++c) {
        double need = (double)NE / c * 1.15 + 4096.0;
        if ((double)capR64 >= need) { C = c; break; }
    }
    int npc = (NN + C - 1) / C;
    int B = C * NR;
    int capRows = capR64 > 2000000000LL ? 2000000000 : (int)capR64;
    int TPC = (int)((double)NE / C * 1.15 / TS) + NR + 8;

    // preprocessing
    k_zero<<<(NN + 255) / 256, 256, 0, stream>>>(bcnt, cursor, ncnt, ncur, hg, gcnt);
    k_hist<<<256, 256, 0, stream>>>(rel, dst, bcnt, ncnt, npc, B);
    k_scan_buckets<<<1, MAXB, 0, stream>>>(bcnt, B, boff, tstart);
    k_scan1<<<NB_SCAN, SCAN_B, 0, stream>>>(ncnt, bsum);
    k_scan2<<<1, 64, 0, stream>>>(bsum, bpref, rowptr);
    k_scan3<<<NB_SCAN, SCAN_B, 0, stream>>>(ncnt, bpref, rowptr);
    k_scatter<<<(NE + 4095) / 4096, 256, 0, stream>>>(rel, dst, boff, cursor, rowptr, ncur, sorted, dpos, npc, B);

    const int RB = (NN + TS - 1) / TS;  // 391

    // layer 0: 128 -> 128 (in h0, out bufA)
    k_selfloop<128, 128><<<dim3(RB, 1), 256, 0, stream>>>(h0, Wl0, b0, bufA);
    for (int c = 0; c < C; ++c) {
        k_edge_msg<128><<<TPC, 256, 0, stream>>>(h0, Wr0, 128, 0, src, sorted, dpos, boff, tstart, rowptr, msg, c, c * npc, capRows);
        k_reduce<<<npc, 128, 0, stream>>>(msg, bufA, 128, 0, rowptr, c * npc, capRows);
    }

    // layer 1: 128 -> 256 (in bufA, out bufB), two 128-col passes
    k_selfloop<128, 256><<<dim3(RB, 2), 256, 0, stream>>>(bufA, Wl1, b1, bufB);
    for (int half = 0; half < 2; ++half) {
        for (int c = 0; c < C; ++c) {
            k_edge_msg<128><<<TPC, 256, 0, stream>>>(bufA, Wr1, 256, half * 128, src, sorted, dpos, boff, tstart, rowptr, msg, c, c * npc, capRows);
            k_reduce<<<npc, 128, 0, stream>>>(msg, bufB, 256, half * 128, rowptr, c * npc, capRows);
        }
    }

    // layer 2: 256 -> 128 (in bufB, out bufA)
    k_selfloop<256, 128><<<dim3(RB, 1), 256, 0, stream>>>(bufB, Wl2, b2, bufA);
    for (int c = 0; c < C; ++c) {
        k_edge_msg<256><<<TPC, 256, 0, stream>>>(bufB, Wr2, 128, 0, src, sorted, dpos, boff, tstart, rowptr, msg, c, c * npc, capRows);
        k_reduce<<<npc, 128, 0, stream>>>(msg, bufA, 128, 0, rowptr, c * npc, capRows);
    }

    // mean pooling per graph
    k_pool<<<RB, 128, 0, stream>>>(bufA, gid, hg, gcnt);
    k_div<<<64, 256, 0, stream>>>(hg, gcnt);

    // MLP head + softmax
    k_mlp<128, 128, true><<<dim3(NG, 1), 256, 0, stream>>>(hg, Wh0, bh0, mlpA);
    k_mlp<128, 256, true><<<dim3(NG, 1), 256, 0, stream>>>(mlpA, Wh1, bh1, mlpB);
    k_mlp<256, 128, true><<<dim3(NG, 1), 256, 0, stream>>>(mlpB, Wh2, bh2, mlpA);
    k_cls<<<(NG + 63) / 64, 64, 0, stream>>>(mlpA, Wc, bc, out);
}

// Round 4
// 1028.515 us; speedup vs baseline: 8.7850x; 1.7604x over previous
//
#include <hip/hip_runtime.h>
#include <stdint.h>

#define NN 50000
#define NE 600000
#define NR 16
#define NG 128
#define TS 128
#define BK 64
#define SCAN_B 512
#define NB_SCAN ((NN + SCAN_B - 1) / SCAN_B)   // 98
#define MAXB 1024

typedef short bf16x8 __attribute__((ext_vector_type(8)));
typedef float f32x4 __attribute__((ext_vector_type(4)));

static __device__ __forceinline__ unsigned short f2bf(float x) {
    unsigned int b = __float_as_uint(x);
    b += 0x7FFFu + ((b >> 16) & 1u);
    return (unsigned short)(b >> 16);
}
static __device__ __forceinline__ float bf2f(unsigned short u) {
    return __uint_as_float(((unsigned int)u) << 16);
}

// ---------------- init / histograms / sort ----------------

__global__ void k_zero(int* bcnt, int* cursor, int* ncnt, int* ncur, float* hg, float* gcnt) {
    int i = blockIdx.x * 256 + threadIdx.x;
    if (i < MAXB) { bcnt[i] = 0; cursor[i] = 0; }
    if (i < NN) { ncnt[i] = 0; ncur[i] = 0; }
    if (i < NG * 128) hg[i] = 0.f;
    if (i < NG) gcnt[i] = 0.f;
}

__global__ void k_hist(const int* __restrict__ rel, const int* __restrict__ dst,
                       int* __restrict__ bcnt, int* __restrict__ ncnt, int npc, int B) {
    __shared__ int lh[MAXB];
    for (int i = threadIdx.x; i < B; i += 256) lh[i] = 0;
    __syncthreads();
    for (int e = blockIdx.x * blockDim.x + threadIdx.x; e < NE; e += gridDim.x * blockDim.x) {
        int d = dst[e];
        atomicAdd(&lh[(d / npc) * NR + rel[e]], 1);
        atomicAdd(&ncnt[d], 1);
    }
    __syncthreads();
    for (int i = threadIdx.x; i < B; i += 256) atomicAdd(&bcnt[i], lh[i]);
}

__global__ void k_scan_buckets(const int* __restrict__ bcnt, int B,
                               int* __restrict__ boff, int* __restrict__ tstart) {
    __shared__ int s1[MAXB], s2[MAXB];
    int tid = threadIdx.x;
    int v1 = (tid < B) ? bcnt[tid] : 0;
    int v2 = (v1 + TS - 1) / TS;
    s1[tid] = v1; s2[tid] = v2;
    __syncthreads();
    for (int off = 1; off < MAXB; off <<= 1) {
        int a1 = (tid >= off) ? s1[tid - off] : 0;
        int a2 = (tid >= off) ? s2[tid - off] : 0;
        __syncthreads();
        s1[tid] += a1; s2[tid] += a2;
        __syncthreads();
    }
    if (tid < B) {
        boff[tid] = s1[tid] - v1;
        tstart[tid] = s2[tid] - v2;
        if (tid == B - 1) { boff[B] = s1[tid]; tstart[B] = s2[tid]; }
    }
}

__global__ void k_scan1(const int* __restrict__ ncnt, int* __restrict__ bsum) {
    __shared__ int s[SCAN_B];
    int i = blockIdx.x * SCAN_B + threadIdx.x;
    s[threadIdx.x] = (i < NN) ? ncnt[i] : 0;
    __syncthreads();
    for (int off = SCAN_B / 2; off > 0; off >>= 1) {
        if (threadIdx.x < off) s[threadIdx.x] += s[threadIdx.x + off];
        __syncthreads();
    }
    if (threadIdx.x == 0) bsum[blockIdx.x] = s[0];
}

__global__ void k_scan2(const int* __restrict__ bsum, int* __restrict__ bpref, int* __restrict__ rowptr) {
    if (threadIdx.x == 0 && blockIdx.x == 0) {
        int run = 0;
        for (int b = 0; b < NB_SCAN; ++b) { bpref[b] = run; run += bsum[b]; }
        rowptr[NN] = run;
    }
}

__global__ void k_scan3(const int* __restrict__ ncnt, const int* __restrict__ bpref,
                        int* __restrict__ rowptr) {
    __shared__ int s[SCAN_B];
    int i = blockIdx.x * SCAN_B + threadIdx.x;
    int val = (i < NN) ? ncnt[i] : 0;
    s[threadIdx.x] = val;
    __syncthreads();
    for (int off = 1; off < SCAN_B; off <<= 1) {
        int x = (threadIdx.x >= off) ? s[threadIdx.x - off] : 0;
        __syncthreads();
        s[threadIdx.x] += x;
        __syncthreads();
    }
    if (i < NN) rowptr[i] = bpref[blockIdx.x] + s[threadIdx.x] - val;
}

__global__ void k_scatter(const int* __restrict__ rel, const int* __restrict__ dst,
                          const int* __restrict__ boff, int* __restrict__ cursor,
                          const int* __restrict__ rowptr, int* __restrict__ ncur,
                          int* __restrict__ sorted, int* __restrict__ dpos, int npc, int B) {
    __shared__ int lh[MAXB];
    const int CH = 4096;
    int e0 = blockIdx.x * CH;
    for (int i = threadIdx.x; i < B; i += 256) lh[i] = 0;
    __syncthreads();
    for (int i = threadIdx.x; i < CH; i += 256) {
        int e = e0 + i;
        if (e < NE) atomicAdd(&lh[(dst[e] / npc) * NR + rel[e]], 1);
    }
    __syncthreads();
    for (int i = threadIdx.x; i < B; i += 256) {
        int c = lh[i];
        lh[i] = (c > 0) ? atomicAdd(&cursor[i], c) : 0;
    }
    __syncthreads();
    for (int i = threadIdx.x; i < CH; i += 256) {
        int e = e0 + i;
        if (e < NE) {
            int d = dst[e];
            int b = (d / npc) * NR + rel[e];
            int p = boff[b] + atomicAdd(&lh[b], 1);
            int pd = rowptr[d] + atomicAdd(&ncur[d], 1);
            sorted[p] = e;
            dpos[p] = pd;
        }
    }
}

// ---------------- conversions ----------------

__global__ void k_hconv(const float* __restrict__ h, unsigned short* __restrict__ hb, int n4) {
    int i = blockIdx.x * 256 + threadIdx.x;
    if (i < n4) {
        float4 v = reinterpret_cast<const float4*>(h)[i];
        ushort4 o = { f2bf(v.x), f2bf(v.y), f2bf(v.z), f2bf(v.w) };
        reinterpret_cast<ushort4*>(hb)[i] = o;
    }
}

// W [R][Kd][Nd] fp32 -> Wt [R][Nd][Kd] bf16
__global__ void k_wconv(const float* __restrict__ W, unsigned short* __restrict__ Wt,
                        int R, int Kd, int Nd) {
    int i = blockIdx.x * 256 + threadIdx.x;
    if (i < R * Kd * Nd) {
        int r = i / (Kd * Nd);
        int rem = i - r * Kd * Nd;
        int k = rem / Nd;
        int n = rem - k * Nd;
        Wt[((size_t)r * Nd + n) * Kd + k] = f2bf(W[i]);
    }
}

// ---------------- MFMA dense GEMM: out = hb @ Wlt^T + bias (fp32 store) ----------------

template<int K>
__global__ __launch_bounds__(256, 4)
void k_dense_mfma(const unsigned short* __restrict__ hb,
                  const unsigned short* __restrict__ Wlt,   // [ldn][K] bf16
                  const float* __restrict__ bias,
                  float* __restrict__ outbuf, int ldn) {
    __shared__ __align__(16) unsigned short As[128][BK + 8];
    __shared__ __align__(16) unsigned short Bs[128][BK + 8];
    const int tid = threadIdx.x;
    const int row0 = blockIdx.x * 128;
    const int colbase = blockIdx.y * 128;
    const int lane = tid & 63, w = tid >> 6;
    const int quad = lane >> 4, col = lane & 15;
    const int srow = tid >> 3, sk = (tid & 7) * 8;

    f32x4 acc[8][2];
#pragma unroll
    for (int i = 0; i < 8; ++i) { acc[i][0] = 0.f; acc[i][1] = 0.f; }

    for (int k0 = 0; k0 < K; k0 += BK) {
        __syncthreads();
#pragma unroll
        for (int pp = 0; pp < 4; ++pp) {
            int rw = pp * 32 + srow;
            int ar = row0 + rw; if (ar >= NN) ar = NN - 1;
            *reinterpret_cast<uint4*>(&As[rw][sk]) =
                *reinterpret_cast<const uint4*>(hb + (size_t)ar * K + k0 + sk);
            *reinterpret_cast<uint4*>(&Bs[rw][sk]) =
                *reinterpret_cast<const uint4*>(Wlt + (size_t)(colbase + rw) * K + k0 + sk);
        }
        __syncthreads();
#pragma unroll
        for (int s = 0; s < 2; ++s) {
            bf16x8 bf0 = *reinterpret_cast<const bf16x8*>(&Bs[w * 32 + col][s * 32 + quad * 8]);
            bf16x8 bf1 = *reinterpret_cast<const bf16x8*>(&Bs[w * 32 + 16 + col][s * 32 + quad * 8]);
#pragma unroll
            for (int rt = 0; rt < 8; ++rt) {
                bf16x8 af = *reinterpret_cast<const bf16x8*>(&As[rt * 16 + col][s * 32 + quad * 8]);
                acc[rt][0] = __builtin_amdgcn_mfma_f32_16x16x32_bf16(af, bf0, acc[rt][0], 0, 0, 0);
                acc[rt][1] = __builtin_amdgcn_mfma_f32_16x16x32_bf16(af, bf1, acc[rt][1], 0, 0, 0);
            }
        }
    }
    float bv0 = bias[colbase + w * 32 + col];
    float bv1 = bias[colbase + w * 32 + 16 + col];
#pragma unroll
    for (int rt = 0; rt < 8; ++rt) {
#pragma unroll
        for (int reg = 0; reg < 4; ++reg) {
            int r = row0 + rt * 16 + quad * 4 + reg;
            if (r < NN) {
                float* dp = outbuf + (size_t)r * ldn + colbase + w * 32;
                dp[col] = acc[rt][0][reg] + bv0;
                dp[16 + col] = acc[rt][1][reg] + bv1;
            }
        }
    }
}

// ---------------- MFMA edge GEMM -> bf16 msg rows at dst-sorted positions ----------------

template<int K>
__global__ __launch_bounds__(256, 4)
void k_edge_mfma(const unsigned short* __restrict__ hb,
                 const unsigned short* __restrict__ Wt,   // [NR][ldn][K] bf16
                 int ldn, int colbase,
                 const int* __restrict__ src,
                 const int* __restrict__ sorted, const int* __restrict__ dpos,
                 const int* __restrict__ boff, const int* __restrict__ tstart,
                 const int* __restrict__ rowptr,
                 unsigned short* __restrict__ msg, int chunk, int n0, int capRows) {
    const int tb0 = tstart[chunk * NR];
    const int tend = tstart[(chunk + 1) * NR];
    const int t = tb0 + blockIdx.x;
    if (t >= tend) return;
    int r = 0;
#pragma unroll
    for (int q = 1; q < NR; ++q) r += (t >= tstart[chunk * NR + q]) ? 1 : 0;
    const int bk = chunk * NR + r;
    const int e0 = boff[bk] + (t - tstart[bk]) * TS;
    int cnt = boff[bk + 1] - e0;
    if (cnt > TS) cnt = TS;

    __shared__ __align__(16) unsigned short As[128][BK + 8];
    __shared__ __align__(16) unsigned short Bs[128][BK + 8];
    __shared__ int s_src[TS], s_out[TS];
    const int tid = threadIdx.x;
    if (tid < TS) {
        int cES = rowptr[n0];
        int valid = tid < cnt;
        int ei = e0 + (valid ? tid : 0);
        int e = sorted[ei];
        s_src[tid] = src[e];
        int row = dpos[ei] - cES;
        s_out[tid] = (valid && row < capRows) ? row : -1;
    }

    const unsigned short* Wb = Wt + ((size_t)r * ldn + colbase) * K;
    const int lane = tid & 63, w = tid >> 6;
    const int quad = lane >> 4, col = lane & 15;
    const int srow = tid >> 3, sk = (tid & 7) * 8;

    f32x4 acc[8][2];
#pragma unroll
    for (int i = 0; i < 8; ++i) { acc[i][0] = 0.f; acc[i][1] = 0.f; }

    for (int k0 = 0; k0 < K; k0 += BK) {
        __syncthreads();
#pragma unroll
        for (int pp = 0; pp < 4; ++pp) {
            int rw = pp * 32 + srow;
            *reinterpret_cast<uint4*>(&As[rw][sk]) =
                *reinterpret_cast<const uint4*>(hb + (size_t)s_src[rw] * K + k0 + sk);
            *reinterpret_cast<uint4*>(&Bs[rw][sk]) =
                *reinterpret_cast<const uint4*>(Wb + (size_t)rw * K + k0 + sk);
        }
        __syncthreads();
#pragma unroll
        for (int s = 0; s < 2; ++s) {
            bf16x8 bf0 = *reinterpret_cast<const bf16x8*>(&Bs[w * 32 + col][s * 32 + quad * 8]);
            bf16x8 bf1 = *reinterpret_cast<const bf16x8*>(&Bs[w * 32 + 16 + col][s * 32 + quad * 8]);
#pragma unroll
            for (int rt = 0; rt < 8; ++rt) {
                bf16x8 af = *reinterpret_cast<const bf16x8*>(&As[rt * 16 + col][s * 32 + quad * 8]);
                acc[rt][0] = __builtin_amdgcn_mfma_f32_16x16x32_bf16(af, bf0, acc[rt][0], 0, 0, 0);
                acc[rt][1] = __builtin_amdgcn_mfma_f32_16x16x32_bf16(af, bf1, acc[rt][1], 0, 0, 0);
            }
        }
    }
#pragma unroll
    for (int rt = 0; rt < 8; ++rt) {
#pragma unroll
        for (int reg = 0; reg < 4; ++reg) {
            int m = rt * 16 + quad * 4 + reg;
            int o = s_out[m];
            if (o >= 0) {
                unsigned short* dp = msg + (size_t)o * 128 + w * 32;
                dp[col] = f2bf(acc[rt][0][reg]);
                dp[16 + col] = f2bf(acc[rt][1][reg]);
            }
        }
    }
}

// segmented reduce over in-chunk dst-sorted bf16 msg rows, fold onto self buffer, relu, in place
__global__ void k_reduce(const unsigned short* __restrict__ msg,
                         float* __restrict__ buf, int ncf, int coloff,
                         const int* __restrict__ rowptr, int n0, int capRows) {
    int n = n0 + blockIdx.x;
    if (n >= NN) return;
    int c = threadIdx.x;
    int cES = rowptr[n0];
    float acc = buf[(size_t)n * ncf + coloff + c];
    int j1 = rowptr[n + 1];
    for (int j = rowptr[n]; j < j1; ++j) {
        int rr = j - cES;
        if (rr >= capRows) break;
        acc += bf2f(msg[(size_t)rr * 128 + c]);
    }
    buf[(size_t)n * ncf + coloff + c] = acc > 0.f ? acc : 0.f;
}

// ---------------- pooling / MLP ----------------

__global__ void k_pool(const float* __restrict__ h, const int* __restrict__ gid,
                       float* __restrict__ hg, float* __restrict__ gcnt) {
    const int c = threadIdx.x;
    int n0 = blockIdx.x * 128;
    if (n0 >= NN) return;
    int cur = gid[n0];
    float run = 0.f, crun = 0.f;
    for (int i = 0; i < 128; ++i) {
        int n = n0 + i;
        if (n >= NN) break;
        int g = gid[n];
        if (g != cur) {
            atomicAdd(&hg[cur * 128 + c], run);
            if (c == 0) atomicAdd(&gcnt[cur], crun);
            run = 0.f; crun = 0.f; cur = g;
        }
        run += h[(size_t)n * 128 + c];
        crun += 1.f;
    }
    atomicAdd(&hg[cur * 128 + c], run);
    if (c == 0) atomicAdd(&gcnt[cur], crun);
}

__global__ void k_div(float* hg, const float* __restrict__ gcnt) {
    int i = blockIdx.x * 256 + threadIdx.x;
    if (i < NG * 128) {
        int g = i >> 7;
        float c = gcnt[g];
        hg[i] /= (c > 1.f ? c : 1.f);
    }
}

template<int DIN, int DOUT, bool RELU>
__global__ void k_mlp(const float* __restrict__ in, const float* __restrict__ W,
                      const float* __restrict__ bias, float* __restrict__ out) {
    int g = blockIdx.x;
    int c = blockIdx.y * 256 + threadIdx.x;
    if (c >= DOUT) return;
    float acc = bias[c];
    for (int k = 0; k < DIN; ++k) acc += in[g * DIN + k] * W[k * DOUT + c];
    if (RELU) acc = acc > 0.f ? acc : 0.f;
    out[g * DOUT + c] = acc;
}

__global__ void k_cls(const float* __restrict__ in, const float* __restrict__ Wc,
                      const float* __restrict__ bc, float* __restrict__ out) {
    int g = blockIdx.x * blockDim.x + threadIdx.x;
    if (g >= NG) return;
    float logit[8];
#pragma unroll
    for (int c = 0; c < 8; ++c) logit[c] = bc[c];
    for (int k = 0; k < 128; ++k) {
        float v = in[g * 128 + k];
#pragma unroll
        for (int c = 0; c < 8; ++c) logit[c] += v * Wc[k * 8 + c];
    }
    float m = logit[0];
#pragma unroll
    for (int c = 1; c < 8; ++c) m = logit[c] > m ? logit[c] : m;
    float s = 0.f;
    float e[8];
#pragma unroll
    for (int c = 0; c < 8; ++c) { e[c] = expf(logit[c] - m); s += e[c]; }
    float inv = 1.f / s;
#pragma unroll
    for (int c = 0; c < 8; ++c) out[g * 8 + c] = e[c] * inv;
}

// ---------------- launcher ----------------

extern "C" void kernel_launch(void* const* d_in, const int* in_sizes, int n_in,
                              void* d_out, int out_size, void* d_ws, size_t ws_size,
                              hipStream_t stream) {
    const float* h0   = (const float*)d_in[0];
    const int* src    = (const int*)d_in[1];
    const int* dst    = (const int*)d_in[2];
    const int* rel    = (const int*)d_in[3];
    const int* gid    = (const int*)d_in[4];
    const float* Wr0  = (const float*)d_in[5];
    const float* Wl0  = (const float*)d_in[6];
    const float* b0   = (const float*)d_in[7];
    const float* Wr1  = (const float*)d_in[8];
    const float* Wl1  = (const float*)d_in[9];
    const float* b1   = (const float*)d_in[10];
    const float* Wr2  = (const float*)d_in[11];
    const float* Wl2  = (const float*)d_in[12];
    const float* b2   = (const float*)d_in[13];
    const float* Wh0  = (const float*)d_in[14];
    const float* bh0  = (const float*)d_in[15];
    const float* Wh1  = (const float*)d_in[16];
    const float* bh1  = (const float*)d_in[17];
    const float* Wh2  = (const float*)d_in[18];
    const float* bh2  = (const float*)d_in[19];
    const float* Wc   = (const float*)d_in[20];
    const float* bc   = (const float*)d_in[21];
    float* out = (float*)d_out;

    // workspace layout (all blocks 256B-aligned)
    char* p = (char*)d_ws;
    auto alloc = [&](size_t bytes) { char* q = p; p += (bytes + 255) & ~(size_t)255; return q; };
    float* bufA  = (float*)alloc((size_t)NN * 128 * 4);
    float* bufB  = (float*)alloc((size_t)NN * 256 * 4);
    unsigned short* hb = (unsigned short*)alloc((size_t)NN * 256 * 2);
    unsigned short* Wt = (unsigned short*)alloc((size_t)NR * 256 * 128 * 2);
    unsigned short* Wlt = (unsigned short*)alloc((size_t)256 * 128 * 2);
    int* sorted  = (int*)alloc((size_t)NE * 4);
    int* dpos    = (int*)alloc((size_t)NE * 4);
    int* ncnt    = (int*)alloc((size_t)NN * 4);
    int* ncur    = (int*)alloc((size_t)NN * 4);
    int* rowptr  = (int*)alloc((size_t)(NN + 1) * 4);
    int* bsum    = (int*)alloc(NB_SCAN * 4);
    int* bpref   = (int*)alloc(NB_SCAN * 4);
    int* bcnt    = (int*)alloc(MAXB * 4);
    int* boff    = (int*)alloc((MAXB + 1) * 4);
    int* tstart  = (int*)alloc((MAXB + 1) * 4);
    int* cursor  = (int*)alloc(MAXB * 4);
    float* hg    = (float*)alloc((size_t)NG * 128 * 4);
    float* gcnt  = (float*)alloc(NG * 4);
    float* mlpA  = (float*)alloc((size_t)NG * 256 * 4);
    float* mlpB  = (float*)alloc((size_t)NG * 256 * 4);
    unsigned short* msg = (unsigned short*)p;

    long long avail = (long long)ws_size - (long long)(p - (char*)d_ws);
    if (avail < (1 << 20)) avail = (1 << 20);
    long long capR64 = avail / 256;                 // bf16 rows of 128
    int C = 64;
    for (int c = 1; c <= 64; ++c) {
        double need = (double)NE / c * 1.15 + 4096.0;
        if ((double)capR64 >= need) { C = c; break; }
    }
    int npc = (NN + C - 1) / C;
    int B = C * NR;
    int capRows = capR64 > 2000000000LL ? 2000000000 : (int)capR64;
    int TPC = (int)((double)NE / C * 1.15 / TS) + NR + 8;

    // preprocessing
    k_zero<<<(NN + 255) / 256, 256, 0, stream>>>(bcnt, cursor, ncnt, ncur, hg, gcnt);
    k_hist<<<256, 256, 0, stream>>>(rel, dst, bcnt, ncnt, npc, B);
    k_scan_buckets<<<1, MAXB, 0, stream>>>(bcnt, B, boff, tstart);
    k_scan1<<<NB_SCAN, SCAN_B, 0, stream>>>(ncnt, bsum);
    k_scan2<<<1, 64, 0, stream>>>(bsum, bpref, rowptr);
    k_scan3<<<NB_SCAN, SCAN_B, 0, stream>>>(ncnt, bpref, rowptr);
    k_scatter<<<(NE + 4095) / 4096, 256, 0, stream>>>(rel, dst, boff, cursor, rowptr, ncur, sorted, dpos, npc, B);

    const int RB = (NN + TS - 1) / TS;  // 391

    // ---- layer 0: 128 -> 128 (in h0, out bufA) ----
    k_hconv<<<(NN * 128 / 4 + 255) / 256, 256, 0, stream>>>(h0, hb, NN * 128 / 4);
    k_wconv<<<(128 * 128 + 255) / 256, 256, 0, stream>>>(Wl0, Wlt, 1, 128, 128);
    k_wconv<<<(NR * 128 * 128 + 255) / 256, 256, 0, stream>>>(Wr0, Wt, NR, 128, 128);
    k_dense_mfma<128><<<dim3(RB, 1), 256, 0, stream>>>(hb, Wlt, b0, bufA, 128);
    for (int c = 0; c < C; ++c) {
        k_edge_mfma<128><<<TPC, 256, 0, stream>>>(hb, Wt, 128, 0, src, sorted, dpos, boff, tstart, rowptr, msg, c, c * npc, capRows);
        k_reduce<<<npc, 128, 0, stream>>>(msg, bufA, 128, 0, rowptr, c * npc, capRows);
    }

    // ---- layer 1: 128 -> 256 (in bufA, out bufB) ----
    k_hconv<<<(NN * 128 / 4 + 255) / 256, 256, 0, stream>>>(bufA, hb, NN * 128 / 4);
    k_wconv<<<(128 * 256 + 255) / 256, 256, 0, stream>>>(Wl1, Wlt, 1, 128, 256);
    k_wconv<<<(NR * 128 * 256 + 255) / 256, 256, 0, stream>>>(Wr1, Wt, NR, 128, 256);
    k_dense_mfma<128><<<dim3(RB, 2), 256, 0, stream>>>(hb, Wlt, b1, bufB, 256);
    for (int half = 0; half < 2; ++half) {
        for (int c = 0; c < C; ++c) {
            k_edge_mfma<128><<<TPC, 256, 0, stream>>>(hb, Wt, 256, half * 128, src, sorted, dpos, boff, tstart, rowptr, msg, c, c * npc, capRows);
            k_reduce<<<npc, 128, 0, stream>>>(msg, bufB, 256, half * 128, rowptr, c * npc, capRows);
        }
    }

    // ---- layer 2: 256 -> 128 (in bufB, out bufA) ----
    k_hconv<<<(NN * 256 / 4 + 255) / 256, 256, 0, stream>>>(bufB, hb, NN * 256 / 4);
    k_wconv<<<(256 * 128 + 255) / 256, 256, 0, stream>>>(Wl2, Wlt, 1, 256, 128);
    k_wconv<<<(NR * 256 * 128 + 255) / 256, 256, 0, stream>>>(Wr2, Wt, NR, 256, 128);
    k_dense_mfma<256><<<dim3(RB, 1), 256, 0, stream>>>(hb, Wlt, b2, bufA, 128);
    for (int c = 0; c < C; ++c) {
        k_edge_mfma<256><<<TPC, 256, 0, stream>>>(hb, Wt, 128, 0, src, sorted, dpos, boff, tstart, rowptr, msg, c, c * npc, capRows);
        k_reduce<<<npc, 128, 0, stream>>>(msg, bufA, 128, 0, rowptr, c * npc, capRows);
    }

    // mean pooling per graph
    k_pool<<<RB, 128, 0, stream>>>(bufA, gid, hg, gcnt);
    k_div<<<64, 256, 0, stream>>>(hg, gcnt);

    // MLP head + softmax
    k_mlp<128, 128, true><<<dim3(NG, 1), 256, 0, stream>>>(hg, Wh0, bh0, mlpA);
    k_mlp<128, 256, true><<<dim3(NG, 1), 256, 0, stream>>>(mlpA, Wh1, bh1, mlpB);
    k_mlp<256, 128, true><<<dim3(NG, 1), 256, 0, stream>>>(mlpB, Wh2, bh2, mlpA);
    k_cls<<<(NG + 63) / 64, 64, 0, stream>>>(mlpA, Wc, bc, out);
}